// Round 7
// baseline (486.538 us; speedup 1.0000x reference)
//
#include <hip/hip_runtime.h>
#include <stdint.h>

// Problem constants
// B=8, H=128, W=128, C=256, HEADS=8, WIN=8, HALO=8, BLOCK=4, PAD=2
// QK_U=32, QK_CH=256, KV_CH=512, M = 8*128*128 = 131072

typedef __attribute__((ext_vector_type(8))) short short8;
typedef __attribute__((ext_vector_type(4))) short short4v;
typedef __attribute__((ext_vector_type(4))) float f32x4;

#define VT_PLANE 4624L   // 68*68

__device__ __forceinline__ float bf2f(unsigned short u){
  union { unsigned int i; float f; } x; x.i = ((unsigned int)u)<<16; return x.f;
}
__device__ __forceinline__ unsigned short f2bf(float f){
  union { float f; unsigned int i; } x; x.f = f;
  unsigned int r = x.i + 0x7FFFu + ((x.i>>16)&1u);
  return (unsigned short)(r>>16);
}
// rounding-pack two f32 -> bf16 pair (lo = a, hi = b)
__device__ __forceinline__ unsigned int pack_bf_r(float a, float b){
  return (unsigned int)f2bf(a) | ((unsigned int)f2bf(b) << 16);
}
// truncation-pack two f32 -> bf16 pair (lo = a, hi = b)
__device__ __forceinline__ unsigned int pack_bf_t(float a, float b){
  union { float f; unsigned int u; } x, y; x.f = a; y.f = b;
  return (y.u & 0xFFFF0000u) | (x.u >> 16);
}
__device__ __forceinline__ void gl_lds16(const void* g, void* l){
  __builtin_amdgcn_global_load_lds((const __attribute__((address_space(1))) unsigned int*)g,
                                   (__attribute__((address_space(3))) unsigned int*)l, 16, 0, 0);
}

// ---------------- f32 -> bf16 streaming convert ------------------------------
__global__ __launch_bounds__(256) void cvt_bf16_kernel(const float* __restrict__ in,
                                                       short* __restrict__ out, long n8)
{
  long stride = (long)gridDim.x * 256;
  for (long i = (long)blockIdx.x*256 + threadIdx.x; i < n8; i += stride){
    float4 a = ((const float4*)in)[2*i];
    float4 b = ((const float4*)in)[2*i+1];
    short8 v;
    v[0]=(short)f2bf(a.x); v[1]=(short)f2bf(a.y); v[2]=(short)f2bf(a.z); v[3]=(short)f2bf(a.w);
    v[4]=(short)f2bf(b.x); v[5]=(short)f2bf(b.y); v[6]=(short)f2bf(b.z); v[7]=(short)f2bf(b.w);
    ((short8*)out)[i] = v;
  }
}

// ---------------- weight transpose + bf16 convert: wt[n][k] = w[k][n] --------
__global__ void transpose_w_kernel(const float* __restrict__ w, short* __restrict__ wt,
                                   int K, int N)
{
  int idx = blockIdx.x*256 + threadIdx.x;
  if (idx >= K*N) return;
  int n = idx / K, k = idx - n*K;
  wt[idx] = (short)f2bf(w[(long)k*N + n]);
}

// ---------------- relative position bias table: out[8][64][64] --------------
// NOTE: output pre-multiplied by 1/ln2 (exp2-domain logits in attention).
__global__ __launch_bounds__(64) void relbias_kernel(const float* __restrict__ w1,
    const float* __restrict__ b1, const float* __restrict__ w2, float* __restrict__ out)
{
  int q = blockIdx.x;   // 0..63  (qy*8+qx)
  int k = threadIdx.x;  // 0..63  (ky*8+kx)
  float ry = (float)(q>>3) - (((float)(k>>3) - 2.f)*2.f + 0.5f);
  float rx = (float)(q&7)  - (((float)(k&7)  - 2.f)*2.f + 0.5f);
  ry *= (8.f/7.f); rx *= (8.f/7.f);
  float sy = (ry>0.f)?1.f:((ry<0.f)?-1.f:0.f);
  float sx = (rx>0.f)?1.f:((rx<0.f)?-1.f:0.f);
  ry = sy * log2f(fabsf(ry)+1.f) * (1.f/3.f);
  rx = sx * log2f(fabsf(rx)+1.f) * (1.f/3.f);
  float acc[8] = {0,0,0,0,0,0,0,0};
  for (int j=0;j<512;j++){
    float hm = ry*w1[j] + rx*w1[512+j] + b1[j];
    hm = fmaxf(hm, 0.f);
#pragma unroll
    for (int h=0;h<8;h++) acc[h] += hm * w2[j*8+h];
  }
#pragma unroll
  for (int h=0;h<8;h++)
    out[h*4096 + q*64 + k] = (16.f / (1.f + __expf(-acc[h]))) * 1.4426950408889634f;
}

// ---------------- GEMM: C[M x ND] = A[M x 256] * Bt[ND x 256]^T --------------
// Barrier-free persistent structure:
//  - B col-block (128x256 bf16 = 64KB) staged to LDS ONCE (chunk-XOR swizzle
//    via pre-swizzled global source), one __syncthreads.
//  - M-loop: A fragments loaded straight to registers (full-64B-line pattern),
//    MFMA with SWAPPED operands (a=B-frag, b=A-frag) so each lane's D regs are
//    4 consecutive output columns -> direct packed stores, no LDS repack,
//    no barriers, waves fully independent (compiler manages counted vmcnt).
template<int ND, int OUTMODE, int MTILES>
__global__ __launch_bounds__(256) void gemm_bt_kernel(const short* __restrict__ A,
    const short* __restrict__ Bt, const float* __restrict__ bias,
    short* __restrict__ out_q, short* __restrict__ out_kv, float* __restrict__ out_f)
{
  __shared__ short smem[32768];    // 64KB: Bt col-block [r=0..127][chunk c=0..31], c XOR (r&7)
  const int tid  = threadIdx.x;
  const int lane = tid & 63;
  const int wid  = tid >> 6;
  const int wr = wid >> 1, wc = wid & 1;
  const int g = lane >> 4, q15 = lane & 15;

  constexpr int NCB = ND / 128;
  constexpr int NSUP_X = (1024 / MTILES) / 8;   // supertiles per XCD
  const int bid = blockIdx.x;
  const int xcd = bid & 7;
  const int idx = bid >> 3;
  const int sup = xcd * NSUP_X + idx / NCB;
  const int col0 = (idx % NCB) * 128;

  // ---- stage B once (16 chunks of 16B per thread) ----
#pragma unroll
  for (int j = 0; j < 16; j++) {
    int f = j*256 + tid;
    int r = f >> 5, c = f & 31;
    gl_lds16(Bt + (long)(col0 + r)*256 + ((c ^ (r&7))<<3),
             smem + ((j*256 + (wid<<6))<<3));
  }
  __syncthreads();

  // ---- bias in registers (4 consecutive cols per lane per nB) ----
  float4 bv[4];
#pragma unroll
  for (int nB=0;nB<4;nB++){
    int cb = col0 + wc*64 + nB*16 + g*4;
    if (OUTMODE == 1 || cb < 256) bv[nB] = *(const float4*)(bias + cb);
    else                          bv[nB] = (float4){0.f,0.f,0.f,0.f};
  }

  for (int t = 0; t < MTILES; t++){
    const long rowt = ((long)sup*MTILES + t)*128;
    const short* Ab = A + (rowt + wr*64 + q15)*256 + g*8;

    f32x4 acc[4][4];
#pragma unroll
    for (int mB=0;mB<4;mB++)
#pragma unroll
      for (int nB=0;nB<4;nB++) acc[mB][nB] = (f32x4){0.f,0.f,0.f,0.f};

#pragma unroll
    for (int half = 0; half < 2; half++){
      short8 af[4][4];                 // [mB][ksl], ks = half*4+ksl
#pragma unroll
      for (int mB=0;mB<4;mB++)
#pragma unroll
        for (int ksl=0;ksl<4;ksl++)
          af[mB][ksl] = *(const short8*)(Ab + mB*16*256 + (half*4+ksl)*32);
#pragma unroll
      for (int ksl=0;ksl<4;ksl++){
        const int ks = half*4 + ksl;
        short8 bf_[4];
#pragma unroll
        for (int nB=0;nB<4;nB++){
          int r = wc*64 + nB*16 + q15;
          int c = (ks*4 + g) ^ (r&7);
          bf_[nB] = *(const short8*)(smem + r*256 + c*8);
        }
#pragma unroll
        for (int mB=0;mB<4;mB++)
#pragma unroll
          for (int nB=0;nB<4;nB++)
            acc[mB][nB] = __builtin_amdgcn_mfma_f32_16x16x32_bf16(bf_[nB], af[mB][ksl], acc[mB][nB], 0, 0, 0);
      }
    }

    // ---- direct stores: row = q15-based, cols = 4 consecutive per reg ----
    if (OUTMODE == 0){
#pragma unroll
      for (int mB=0;mB<4;mB++){
        long row = rowt + wr*64 + mB*16 + q15;
#pragma unroll
        for (int nB=0;nB<4;nB++){
          int col = col0 + wc*64 + nB*16 + g*4;
          uint2 pk;
          pk.x = pack_bf_r(acc[mB][nB][0]+bv[nB].x, acc[mB][nB][1]+bv[nB].y);
          pk.y = pack_bf_r(acc[mB][nB][2]+bv[nB].z, acc[mB][nB][3]+bv[nB].w);
          if (col0 < 256) *(uint2*)(out_q + row*256 + col)        = pk;
          else            *(uint2*)(out_kv + row*512 + (col-256)) = pk;
        }
      }
    } else {
#pragma unroll
      for (int mB=0;mB<4;mB++){
        long row = rowt + wr*64 + mB*16 + q15;
#pragma unroll
        for (int nB=0;nB<4;nB++){
          int col = col0 + wc*64 + nB*16 + g*4;
          float4 o;
          o.x = acc[mB][nB][0]+bv[nB].x; o.y = acc[mB][nB][1]+bv[nB].y;
          o.z = acc[mB][nB][2]+bv[nB].z; o.w = acc[mB][nB][3]+bv[nB].w;
          *(float4*)(out_f + row*ND + col) = o;
        }
      }
    }
  }
}

// ---------------- depthwise 3x3 stride-2 conv + BN + v_bias ------------------
// in: kv_buf bf16 (8,128,128,512)
// out K: kv_K (8,64,64,256) row-major
// out V: v_t  (8 b, 8 h, 32 d, 68, 68) bf16, interior [2..65]^2 (borders unused)
// V path goes through an LDS transpose so global stores are plane-row chunks.
__global__ __launch_bounds__(256) void dwconv_kernel(const short* __restrict__ kv_buf,
    const float* __restrict__ dw_w, const float* __restrict__ gamma,
    const float* __restrict__ beta, const float* __restrict__ mean,
    const float* __restrict__ var, const float* __restrict__ v_bias,
    short* __restrict__ kv_K, short* __restrict__ v_t)
{
  __shared__ short vls[32][256];       // [x-local][v-channel]

  const int bid = blockIdx.x;          // 8*64*2 = 1024 blocks
  const int b  = bid >> 7;
  const int rem = bid & 127;
  const int y2 = rem >> 1, xq = rem & 1;
  const int tid = threadIdx.x;
  const int lane = tid & 63, w = tid >> 6;
  const int ch0 = lane * 8;            // 8 channels per lane

  float s[8], sh[8];
#pragma unroll
  for (int i=0;i<8;i+=4){
    float4 g4 = *(const float4*)(gamma + ch0 + i);
    float4 v4 = *(const float4*)(var   + ch0 + i);
    float4 m4 = *(const float4*)(mean  + ch0 + i);
    float4 b4 = *(const float4*)(beta  + ch0 + i);
    float gg[4] = {g4.x,g4.y,g4.z,g4.w}, vv[4] = {v4.x,v4.y,v4.z,v4.w};
    float mm[4] = {m4.x,m4.y,m4.z,m4.w}, bb[4] = {b4.x,b4.y,b4.z,b4.w};
#pragma unroll
    for (int j=0;j<4;j++){
      float sv = gg[j] * rsqrtf(vv[j] + 1e-3f);
      s[i+j]  = sv;
      sh[i+j] = bb[j] - mm[j]*sv;
    }
  }
  if (ch0 >= 256){
    float4 vb0 = *(const float4*)(v_bias + ch0 - 256);
    float4 vb1 = *(const float4*)(v_bias + ch0 - 252);
    sh[0]+=vb0.x; sh[1]+=vb0.y; sh[2]+=vb0.z; sh[3]+=vb0.w;
    sh[4]+=vb1.x; sh[5]+=vb1.y; sh[6]+=vb1.z; sh[7]+=vb1.w;
  }

  float wv[9][8];
#pragma unroll
  for (int t=0;t<9;t++){
    float4 w0 = *(const float4*)(dw_w + t*512 + ch0);
    float4 w1 = *(const float4*)(dw_w + t*512 + ch0 + 4);
    wv[t][0]=w0.x; wv[t][1]=w0.y; wv[t][2]=w0.z; wv[t][3]=w0.w;
    wv[t][4]=w1.x; wv[t][5]=w1.y; wv[t][6]=w1.z; wv[t][7]=w1.w;
  }

  const int y0 = y2*2;
  const bool vy2 = (y0 + 2) < 128;
  const short* r0 = kv_buf + (((long)b*128 + y0)*128)*512 + ch0;
  const short* r1 = r0 + 128*512;
  const short* r2 = r1 + 128*512;
  const short8 zero8 = {0,0,0,0,0,0,0,0};

  const int x2base = xq*32 + w*8;
  const int xs = x2base*2;

  auto ld = [&](const short* r, int x, bool vy)->short8 {
    if (vy && x < 128) return *(const short8*)(r + (long)x*512);
    return zero8;
  };

  short8 L0 = ld(r0, xs, true), L1 = ld(r1, xs, true), L2 = ld(r2, xs, vy2);

#pragma unroll
  for (int i=0;i<8;i++){
    const int x2 = x2base + i;
    const int xm = xs + 2*i + 1, xr = xs + 2*i + 2;
    short8 M0 = ld(r0, xm, true), M1 = ld(r1, xm, true), M2 = ld(r2, xm, vy2);
    short8 R0 = ld(r0, xr, true), R1 = ld(r1, xr, true), R2 = ld(r2, xr, vy2);

    float acc[8];
#pragma unroll
    for (int c=0;c<8;c++) acc[c] = 0.f;
#pragma unroll
    for (int c=0;c<8;c++){
      acc[c] += bf2f((unsigned short)L0[c]) * wv[0][c];
      acc[c] += bf2f((unsigned short)M0[c]) * wv[1][c];
      acc[c] += bf2f((unsigned short)R0[c]) * wv[2][c];
      acc[c] += bf2f((unsigned short)L1[c]) * wv[3][c];
      acc[c] += bf2f((unsigned short)M1[c]) * wv[4][c];
      acc[c] += bf2f((unsigned short)R1[c]) * wv[5][c];
      acc[c] += bf2f((unsigned short)L2[c]) * wv[6][c];
      acc[c] += bf2f((unsigned short)M2[c]) * wv[7][c];
      acc[c] += bf2f((unsigned short)R2[c]) * wv[8][c];
    }
    short8 o;
#pragma unroll
    for (int c=0;c<8;c++) o[c] = (short)f2bf(acc[c]*s[c] + sh[c]);

    if (ch0 < 256) {
      *(short8*)(kv_K + ((long)((b*64+y2)*64 + x2))*256 + ch0) = o;
    } else {
      *(short8*)(&vls[w*8 + i][ch0 - 256]) = o;
    }
    L0 = R0; L1 = R1; L2 = R2;
  }

  __syncthreads();
  {
    const int cc = tid, hh = cc >> 5, d0 = cc & 31;
    long base = ((long)((b*8+hh)*32 + d0))*VT_PLANE + (long)(y2+2)*68 + xq*32 + 2;
#pragma unroll
    for (int j=0;j<16;j++){
      short2 pr;
      pr.x = vls[2*j][cc];
      pr.y = vls[2*j+1][cc];
      *(short2*)(v_t + base + 2*j) = pr;
    }
  }
}

// ---------------- halo attention ---------------------------------------------
// grid 2048 (= 8 batch * 256 windows); 4 waves, wave w -> heads {w, w+4}.
// No barriers; per-wave 8KB XOR-swizzled P in LDS; V from v_t (padded planes);
// in-register norms; exp2-domain logits; O^T epilogue with 8B packed stores.
__global__ __launch_bounds__(256) void halo_attn_kernel(const short* __restrict__ q_buf,
    const short* __restrict__ kv_K, const short* __restrict__ v_t,
    const float* __restrict__ relb, const float* __restrict__ scale,
    short* __restrict__ attn_out)
{
  __shared__ short ps[4][4096];   // per-wave P~ [64 q][64 k] bf16, chunk-swizzled

  const int bid = blockIdx.x;
  const int b = bid >> 8, wno = bid & 255;
  const int bi = wno >> 4, bj = wno & 15;
  const int tid = threadIdx.x;
  const int w = tid >> 6, lane = tid & 63;
  const int g = lane >> 4, q15 = lane & 15;
  short* myps = &ps[w][0];
  const short8 zero8 = {0,0,0,0,0,0,0,0};

  // ---- head-independent per-lane geometry ----
  long kbase[4]; bool kval[4];
#pragma unroll
  for (int m=0;m<4;m++){
    int key = m*16 + q15;
    int yy = bi*4-2 + (key>>3), xx = bj*4-2 + (key&7);
    kval[m] = (yy>=0 && yy<64 && xx>=0 && xx<64);
    kbase[m] = ((long)((b*64+yy)*64+xx))*256 + g*8;
  }
  float mkv[4][4];            // mask in D-layout: key = m*16+g*4+r
#pragma unroll
  for (int m=0;m<4;m++)
#pragma unroll
    for (int r=0;r<4;r++){
      int key = m*16 + g*4 + r;
      int yy = bi*4-2+(key>>3), xx = bj*4-2+(key&7);
      mkv[m][r] = (yy>=0&&yy<64&&xx>=0&&xx<64) ? 0.f : -30000.f;
    }
  long qpix[4];
#pragma unroll
  for (int n=0;n<4;n++){
    int q = n*16+q15;
    qpix[n] = ((long)((b*128+bi*8+(q>>3))*128 + bj*8+(q&7)))*256;
  }
  int voff[2];
#pragma unroll
  for (int ks=0;ks<2;ks++) voff[ks] = (bi*4+ks*4+g)*68 + bj*4;

  for (int hi=0; hi<2; hi++){
    const int h = w + hi*4;
    const float lsc = __expf(fminf(scale[h], 4.6051702f)) * 1.4426950408889634f;

    // ---- V^T A-fragments straight from v_t (issue early; 16B each) ----
    short8 va[2][2];
#pragma unroll
    for (int dblk=0;dblk<2;dblk++){
      long pl = ((long)((b*8+h)*32 + dblk*16 + q15))*VT_PLANE;
#pragma unroll
      for (int ks=0;ks<2;ks++)
        va[dblk][ks] = *(const short8*)(v_t + pl + voff[ks]);
    }

    // ---- K fragments + in-register k norms ----
    short8 af[4]; float rkk[4];
#pragma unroll
    for (int m=0;m<4;m++){
      af[m] = kval[m] ? *(const short8*)(kv_K + kbase[m] + h*32) : zero8;
      float ss = 0.f;
#pragma unroll
      for (int e=0;e<8;e++){ float f = bf2f((unsigned short)af[m][e]); ss += f*f; }
      ss += __shfl_xor(ss, 16);
      ss += __shfl_xor(ss, 32);
      rkk[m] = rsqrtf(fmaxf(ss, 1.55e-5f));
    }
    // ---- Q fragments + in-register q norms (lscale/ln2 folded in) ----
    short8 bfv[4]; float rq[4];
#pragma unroll
    for (int n=0;n<4;n++){
      bfv[n] = *(const short8*)(q_buf + qpix[n] + h*32 + g*8);
      float ss = 0.f;
#pragma unroll
      for (int e=0;e<8;e++){ float f = bf2f((unsigned short)bfv[n][e]); ss += f*f; }
      ss += __shfl_xor(ss, 16);
      ss += __shfl_xor(ss, 32);
      rq[n] = rsqrtf(fmaxf(ss, 1.55e-5f)) * lsc;
    }
    // redistribute k-norms to D-layout (key = m*16+g*4+r)
    float rk[4][4];
#pragma unroll
    for (int m=0;m<4;m++)
#pragma unroll
      for (int r=0;r<4;r++)
        rk[m][r] = __shfl(rkk[m], ((lane>>4)<<2) + r);

    // ---- S^T = K*Q^T ----
    f32x4 sc[4][4];
#pragma unroll
    for (int m=0;m<4;m++)
#pragma unroll
      for (int n=0;n<4;n++)
        sc[m][n] = __builtin_amdgcn_mfma_f32_16x16x32_bf16(af[m], bfv[n],
                       (f32x4){0.f,0.f,0.f,0.f}, 0, 0, 0);

    // ---- logits (exp2 domain) + max ----
    float mx[4] = {-3e38f,-3e38f,-3e38f,-3e38f};
#pragma unroll
    for (int m=0;m<4;m++){
#pragma unroll
      for (int n=0;n<4;n++){
        f32x4 rb = *(const f32x4*)(relb + h*4096 + (n*16+q15)*64 + m*16 + g*4);
#pragma unroll
        for (int r=0;r<4;r++){
          float v = sc[m][n][r] * (rk[m][r]*rq[n]) + rb[r] + mkv[m][r];
          sc[m][n][r] = v;
          mx[n] = fmaxf(mx[n], v);
        }
      }
    }
#pragma unroll
    for (int n=0;n<4;n++){
      mx[n] = fmaxf(mx[n], __shfl_xor(mx[n], 16));
      mx[n] = fmaxf(mx[n], __shfl_xor(mx[n], 32));
    }
    float sm[4] = {0.f,0.f,0.f,0.f};
#pragma unroll
    for (int m=0;m<4;m++)
#pragma unroll
      for (int n=0;n<4;n++)
#pragma unroll
        for (int r=0;r<4;r++){
          float e = exp2f(sc[m][n][r] - mx[n]);
          sc[m][n][r] = e;
          sm[n] += e;
        }
    float sminv[4];
#pragma unroll
    for (int n=0;n<4;n++){
      sm[n] += __shfl_xor(sm[n], 16);
      sm[n] += __shfl_xor(sm[n], 32);
      sminv[n] = 1.f / sm[n];
    }

    // ---- pack P~ (unnormalized, <=1) to LDS, chunk-swizzled ----
#pragma unroll
    for (int n=0;n<4;n++){
      int row = n*16 + q15;
#pragma unroll
      for (int m=0;m<4;m++){
        uint2 pk;
        pk.x = pack_bf_t(sc[m][n][0], sc[m][n][1]);
        pk.y = pack_bf_t(sc[m][n][2], sc[m][n][3]);
        int kc = (m*2 + (g>>1)) ^ (row & 7);
        *(uint2*)(myps + row*64 + kc*8 + ((g&1)<<2)) = pk;
      }
    }
    asm volatile("s_waitcnt lgkmcnt(0)" ::: "memory");

    // ---- O^T = mfma(V^T, P) ----
    f32x4 oc[2][4];
#pragma unroll
    for (int dblk=0;dblk<2;dblk++)
#pragma unroll
      for (int n=0;n<4;n++) oc[dblk][n] = (f32x4){0.f,0.f,0.f,0.f};
#pragma unroll
    for (int ks=0;ks<2;ks++){
#pragma unroll
      for (int n=0;n<4;n++){
        int row = n*16 + q15;
        short8 pb = *(const short8*)(myps + row*64 + (((ks*4+g) ^ (row&7))<<3));
#pragma unroll
        for (int dblk=0;dblk<2;dblk++)
          oc[dblk][n] = __builtin_amdgcn_mfma_f32_16x16x32_bf16(va[dblk][ks], pb, oc[dblk][n], 0, 0, 0);
      }
    }

    // ---- store O (normalize by 1/sum, pack 4 consecutive d = 8B) ----
#pragma unroll
    for (int dblk=0;dblk<2;dblk++){
#pragma unroll
      for (int n=0;n<4;n++){
        uint2 pk;
        pk.x = pack_bf_t(oc[dblk][n][0]*sminv[n], oc[dblk][n][1]*sminv[n]);
        pk.y = pack_bf_t(oc[dblk][n][2]*sminv[n], oc[dblk][n][3]*sminv[n]);
        *(uint2*)(attn_out + qpix[n] + h*32 + dblk*16 + g*4) = pk;
      }
    }
  }
}

// ---------------- launch -----------------------------------------------------
extern "C" void kernel_launch(void* const* d_in, const int* in_sizes, int n_in,
                              void* d_out, int out_size, void* d_ws, size_t ws_size,
                              hipStream_t stream)
{
  (void)in_sizes; (void)n_in; (void)out_size; (void)ws_size;
  const float* inputs = (const float*)d_in[0];
  const float* qkv_w  = (const float*)d_in[1];
  const float* q_bias = (const float*)d_in[2];
  const float* v_bias = (const float*)d_in[3];
  const float* dw_w   = (const float*)d_in[4];
  const float* dw_g   = (const float*)d_in[5];
  const float* dw_b   = (const float*)d_in[6];
  const float* dw_m   = (const float*)d_in[7];
  const float* dw_v   = (const float*)d_in[8];
  const float* scale  = (const float*)d_in[9];
  const float* cpb_w1 = (const float*)d_in[10];
  const float* cpb_b1 = (const float*)d_in[11];
  const float* cpb_w2 = (const float*)d_in[12];
  const float* proj_w = (const float*)d_in[13];
  const float* proj_b = (const float*)d_in[14];

  char* ws = (char*)d_ws;
  short* q_buf    = (short*)(ws);                  //  64 MiB (131072 x 256)
  short* kv_buf   = (short*)(ws + 67108864L);      // 128 MiB (131072 x 512)
  short* kv_K     = (short*)(ws + 201326592L);     //  16 MiB (8x64x64x256)
  short* v_t      = (short*)(ws + 218103808L);     //  ~18 MiB (8*8*32 x 68 x 68)
  short* attn_buf = (short*)(ws + 237043712L);     //  64 MiB (131072 x 256)
  short* qkvw_t   = (short*)(ws + 304152576L);     // 768 KiB
  short* projw_t  = (short*)(ws + 304939008L);     // 128 KiB
  float* relb     = (float*)(ws + 305070080L);     // 128 KiB

  // a_bf reuses the attn_buf region (dead until attention writes it).
  short* a_bf = attn_buf;

  cvt_bf16_kernel<<<2048, 256, 0, stream>>>(inputs, a_bf, 4194304L);
  transpose_w_kernel<<<768, 256, 0, stream>>>(qkv_w, qkvw_t, 256, 768);
  transpose_w_kernel<<<256, 256, 0, stream>>>(proj_w, projw_t, 256, 256);
  relbias_kernel<<<64, 64, 0, stream>>>(cpb_w1, cpb_b1, cpb_w2, relb);

  gemm_bt_kernel<768, 0, 4><<<1536, 256, 0, stream>>>(
      a_bf, qkvw_t, q_bias, q_buf, kv_buf, nullptr);

  dwconv_kernel<<<1024, 256, 0, stream>>>(kv_buf, dw_w, dw_g, dw_b, dw_m, dw_v, v_bias,
                                          kv_K, v_t);

  halo_attn_kernel<<<2048, 256, 0, stream>>>(q_buf, kv_K, v_t, relb, scale, attn_buf);

  gemm_bt_kernel<256, 1, 4><<<512, 256, 0, stream>>>(
      attn_buf, projw_t, proj_b, nullptr, nullptr, (float*)d_out);
}

// Round 10
// 408.059 us; speedup vs baseline: 1.1923x; 1.1923x over previous
//
#include <hip/hip_runtime.h>
#include <stdint.h>

// Problem constants
// B=8, H=128, W=128, C=256, HEADS=8, WIN=8, HALO=8, BLOCK=4, PAD=2
// QK_U=32, QK_CH=256, KV_CH=512, M = 8*128*128 = 131072

typedef __attribute__((ext_vector_type(8))) short short8;
typedef __attribute__((ext_vector_type(4))) short short4v;
typedef __attribute__((ext_vector_type(4))) float f32x4;

#define VT_PLANE 4624L   // 68*68

__device__ __forceinline__ float bf2f(unsigned short u){
  union { unsigned int i; float f; } x; x.i = ((unsigned int)u)<<16; return x.f;
}
__device__ __forceinline__ unsigned short f2bf(float f){
  union { float f; unsigned int i; } x; x.f = f;
  unsigned int r = x.i + 0x7FFFu + ((x.i>>16)&1u);
  return (unsigned short)(r>>16);
}
// truncation-pack two f32 -> bf16 pair (lo = a, hi = b)
__device__ __forceinline__ unsigned int pack_bf_t(float a, float b){
  union { float f; unsigned int u; } x, y; x.f = a; y.f = b;
  return (y.u & 0xFFFF0000u) | (x.u >> 16);
}
__device__ __forceinline__ void gl_lds16(const void* g, void* l){
  __builtin_amdgcn_global_load_lds((const __attribute__((address_space(1))) unsigned int*)g,
                                   (__attribute__((address_space(3))) unsigned int*)l, 16, 0, 0);
}

// ---------------- f32 -> bf16 streaming convert ------------------------------
__global__ __launch_bounds__(256) void cvt_bf16_kernel(const float* __restrict__ in,
                                                       short* __restrict__ out, long n8)
{
  long stride = (long)gridDim.x * 256;
  for (long i = (long)blockIdx.x*256 + threadIdx.x; i < n8; i += stride){
    float4 a = ((const float4*)in)[2*i];
    float4 b = ((const float4*)in)[2*i+1];
    short8 v;
    v[0]=(short)f2bf(a.x); v[1]=(short)f2bf(a.y); v[2]=(short)f2bf(a.z); v[3]=(short)f2bf(a.w);
    v[4]=(short)f2bf(b.x); v[5]=(short)f2bf(b.y); v[6]=(short)f2bf(b.z); v[7]=(short)f2bf(b.w);
    ((short8*)out)[i] = v;
  }
}

// ---------------- weight transpose + bf16 convert: wt[n][k] = w[k][n] --------
__global__ void transpose_w_kernel(const float* __restrict__ w, short* __restrict__ wt,
                                   int K, int N)
{
  int idx = blockIdx.x*256 + threadIdx.x;
  if (idx >= K*N) return;
  int n = idx / K, k = idx - n*K;
  wt[idx] = (short)f2bf(w[(long)k*N + n]);
}

// ---------------- relative position bias table: out[8][64][64] --------------
// NOTE: output pre-multiplied by 1/ln2 (exp2-domain logits in attention).
__global__ __launch_bounds__(64) void relbias_kernel(const float* __restrict__ w1,
    const float* __restrict__ b1, const float* __restrict__ w2, float* __restrict__ out)
{
  int q = blockIdx.x;   // 0..63  (qy*8+qx)
  int k = threadIdx.x;  // 0..63  (ky*8+kx)
  float ry = (float)(q>>3) - (((float)(k>>3) - 2.f)*2.f + 0.5f);
  float rx = (float)(q&7)  - (((float)(k&7)  - 2.f)*2.f + 0.5f);
  ry *= (8.f/7.f); rx *= (8.f/7.f);
  float sy = (ry>0.f)?1.f:((ry<0.f)?-1.f:0.f);
  float sx = (rx>0.f)?1.f:((rx<0.f)?-1.f:0.f);
  ry = sy * log2f(fabsf(ry)+1.f) * (1.f/3.f);
  rx = sx * log2f(fabsf(rx)+1.f) * (1.f/3.f);
  float acc[8] = {0,0,0,0,0,0,0,0};
  for (int j=0;j<512;j++){
    float hm = ry*w1[j] + rx*w1[512+j] + b1[j];
    hm = fmaxf(hm, 0.f);
#pragma unroll
    for (int h=0;h<8;h++) acc[h] += hm * w2[j*8+h];
  }
#pragma unroll
  for (int h=0;h<8;h++)
    out[h*4096 + q*64 + k] = (16.f / (1.f + __expf(-acc[h]))) * 1.4426950408889634f;
}

// ---------------- GEMM: C[M x ND] = A[M x 256] * Bt[ND x 256]^T --------------
// T3/T4 structure: BK=32, 3-buffer LDS ring (48KB -> 3 blocks/CU), raw
// s_barrier (with "memory" fence semantics) + counted vmcnt. Per K-step t:
//   s_waitcnt vmcnt(4) lgkmcnt(0)
//     [stage t landed (mine); stage t+1 in flight; my compute(t-1) LDS reads done]
//   s_barrier (asm w/ memory clobber -> no ds_read hoist above it)
//   issue stage(t+2) -> buf (t+2)%3 (the buffer consumed at t-1)
//   compute(t) from buf t%3
// LDS tile layout: row r (0..127) = 64 BYTES (4 x 16B chunks); chunk c holds
// source chunk c ^ ((r>>1)&3) (bank window = 128B = 2 rows -> XOR on r>>1).
template<int ND, int OUTMODE>
__global__ __launch_bounds__(256) void gemm_bt_kernel(const short* __restrict__ A,
    const short* __restrict__ Bt, const float* __restrict__ bias,
    short* __restrict__ out_q, short* __restrict__ out_kv, float* __restrict__ out_f)
{
  __shared__ short smem[24576];   // 3 bufs x (A 4096 | B 4096 shorts) = 48KB
  const int tid  = threadIdx.x;
  const int lane = tid & 63;
  const int wid  = tid >> 6;
  const int wr = wid >> 1, wc = wid & 1;
  const int g = lane >> 4, q15 = lane & 15;

  constexpr int NCB = ND / 128;
  const int bid = blockIdx.x;
  const int xcd = bid & 7;
  const int idx = bid >> 3;
  const long row0 = (long)(xcd * 128 + idx / NCB) * 128;
  const int  col0 = (idx % NCB) * 128;

  f32x4 acc[4][4];
#pragma unroll
  for (int m=0;m<4;m++)
#pragma unroll
    for (int n=0;n<4;n++) acc[m][n] = (f32x4){0.f,0.f,0.f,0.f};

  auto stage = [&](int s){
    int buf = s % 3;
    int kt = s * 32;
#pragma unroll
    for (int j = 0; j < 2; j++) {
      int f = j*256 + tid;               // 16B-chunk index (512 chunks per matrix)
      int r = f >> 2, c = f & 3;
      int cs = c ^ ((r>>1)&3);
      gl_lds16(A + (row0 + r)*256 + kt + (cs<<3),
               smem + buf*8192 + ((j*256 + (wid<<6))<<3));
      gl_lds16(Bt + (long)(col0 + r)*256 + kt + (cs<<3),
               smem + buf*8192 + 4096 + ((j*256 + (wid<<6))<<3));
    }
  };
  auto compute = [&](int s){
    const short* As = smem + (s%3)*8192;
    const short* Bs = As + 4096;
    short8 af[4], bfv[4];
#pragma unroll
    for (int m=0;m<4;m++){
      int r = wr*64 + m*16 + q15;
      af[m] = *(const short8*)(As + (r<<5) + ((g ^ ((r>>1)&3))<<3));
    }
#pragma unroll
    for (int n=0;n<4;n++){
      int r = wc*64 + n*16 + q15;
      bfv[n] = *(const short8*)(Bs + (r<<5) + ((g ^ ((r>>1)&3))<<3));
    }
#pragma unroll
    for (int m=0;m<4;m++)
#pragma unroll
      for (int n=0;n<4;n++)
        acc[m][n] = __builtin_amdgcn_mfma_f32_16x16x32_bf16(af[m], bfv[n], acc[m][n], 0, 0, 0);
  };

  stage(0);
  stage(1);
#pragma unroll
  for (int t = 0; t < 8; t++){
    if (t < 7) asm volatile("s_waitcnt vmcnt(4) lgkmcnt(0)" ::: "memory");
    else       asm volatile("s_waitcnt vmcnt(0) lgkmcnt(0)" ::: "memory");
    asm volatile("s_barrier" ::: "memory");
    if (t + 2 < 8) stage(t + 2);
    compute(t);
  }
  asm volatile("s_waitcnt lgkmcnt(0)" ::: "memory");
  asm volatile("s_barrier" ::: "memory");   // all computes done before scratch reuse

  // epilogue. C/D frag layout: col=lane&15, row=(lane>>4)*4+reg
  if (OUTMODE == 0) {
    short* sc = smem;            // 16384 shorts scratch (bufs 0+1)
#pragma unroll
    for (int m=0;m<4;m++){
#pragma unroll
      for (int n=0;n<4;n++){
        int col = wc*64 + n*16 + q15;
        int cg = col >> 3;
        float bv = (col0 + col < 256) ? bias[col0 + col] : 0.f;
#pragma unroll
        for (int rg=0;rg<4;rg++){
          int row = wr*64 + m*16 + g*4 + rg;
          sc[row*128 + ((cg ^ (row&7))<<3) + (col&7)] = (short)f2bf(acc[m][n][rg] + bv);
        }
      }
    }
    __syncthreads();
    int row = tid >> 1, ch = tid & 1;
    long grow = row0 + row;
#pragma unroll
    for (int j=0;j<8;j++){
      int cg = ch*8 + j;
      short8 v = *(const short8*)(sc + row*128 + ((cg ^ (row&7))<<3));
      int col = col0 + cg*8;
      if (col0 < 256) *(short8*)(out_q + grow*256 + col)        = v;
      else            *(short8*)(out_kv + grow*512 + (col-256)) = v;
    }
  } else {
    float* fsc = (float*)smem;   // 8192 floats = 64 rows x 128 (32KB)
#pragma unroll
    for (int p=0;p<2;p++){
      if (wr == p){
#pragma unroll
        for (int m=0;m<4;m++){
#pragma unroll
          for (int n=0;n<4;n++){
            int col = wc*64 + n*16 + q15;
            int c4 = col >> 2;
            float bv = bias[col0 + col];
#pragma unroll
            for (int rg=0;rg<4;rg++){
              int rl = m*16 + g*4 + rg;   // 0..63
              fsc[rl*128 + ((c4 ^ (rl&7))<<2) + (col&3)] = acc[m][n][rg] + bv;
            }
          }
        }
      }
      __syncthreads();
      {
        int rl = tid >> 2;
        long grow = row0 + p*64 + rl;
#pragma unroll
        for (int j=0;j<8;j++){
          int c4 = (tid&3)*8 + j;
          float4 v = *(const float4*)(fsc + rl*128 + ((c4 ^ (rl&7))<<2));
          *(float4*)(out_f + grow*ND + col0 + c4*4) = v;
        }
      }
      __syncthreads();
    }
  }
}

// ---------------- depthwise 3x3 stride-2 conv + BN + v_bias ------------------
// in: kv_buf bf16 (8,128,128,512)
// out K: kv_K (8,64,64,256) row-major
// out V: v_t  (8 b, 8 h, 32 d, 68, 68) bf16, interior [2..65]^2 (borders unused)
// V path goes through an LDS transpose so global stores are plane-row chunks.
__global__ __launch_bounds__(256) void dwconv_kernel(const short* __restrict__ kv_buf,
    const float* __restrict__ dw_w, const float* __restrict__ gamma,
    const float* __restrict__ beta, const float* __restrict__ mean,
    const float* __restrict__ var, const float* __restrict__ v_bias,
    short* __restrict__ kv_K, short* __restrict__ v_t)
{
  __shared__ short vls[32][256];       // [x-local][v-channel]

  const int bid = blockIdx.x;          // 8*64*2 = 1024 blocks
  const int b  = bid >> 7;
  const int rem = bid & 127;
  const int y2 = rem >> 1, xq = rem & 1;
  const int tid = threadIdx.x;
  const int lane = tid & 63, w = tid >> 6;
  const int ch0 = lane * 8;            // 8 channels per lane

  float s[8], sh[8];
#pragma unroll
  for (int i=0;i<8;i+=4){
    float4 g4 = *(const float4*)(gamma + ch0 + i);
    float4 v4 = *(const float4*)(var   + ch0 + i);
    float4 m4 = *(const float4*)(mean  + ch0 + i);
    float4 b4 = *(const float4*)(beta  + ch0 + i);
    float gg[4] = {g4.x,g4.y,g4.z,g4.w}, vv[4] = {v4.x,v4.y,v4.z,v4.w};
    float mm[4] = {m4.x,m4.y,m4.z,m4.w}, bb[4] = {b4.x,b4.y,b4.z,b4.w};
#pragma unroll
    for (int j=0;j<4;j++){
      float sv = gg[j] * rsqrtf(vv[j] + 1e-3f);
      s[i+j]  = sv;
      sh[i+j] = bb[j] - mm[j]*sv;
    }
  }
  if (ch0 >= 256){
    float4 vb0 = *(const float4*)(v_bias + ch0 - 256);
    float4 vb1 = *(const float4*)(v_bias + ch0 - 252);
    sh[0]+=vb0.x; sh[1]+=vb0.y; sh[2]+=vb0.z; sh[3]+=vb0.w;
    sh[4]+=vb1.x; sh[5]+=vb1.y; sh[6]+=vb1.z; sh[7]+=vb1.w;
  }

  float wv[9][8];
#pragma unroll
  for (int t=0;t<9;t++){
    float4 w0 = *(const float4*)(dw_w + t*512 + ch0);
    float4 w1 = *(const float4*)(dw_w + t*512 + ch0 + 4);
    wv[t][0]=w0.x; wv[t][1]=w0.y; wv[t][2]=w0.z; wv[t][3]=w0.w;
    wv[t][4]=w1.x; wv[t][5]=w1.y; wv[t][6]=w1.z; wv[t][7]=w1.w;
  }

  const int y0 = y2*2;
  const bool vy2 = (y0 + 2) < 128;
  const short* r0 = kv_buf + (((long)b*128 + y0)*128)*512 + ch0;
  const short* r1 = r0 + 128*512;
  const short* r2 = r1 + 128*512;
  const short8 zero8 = {0,0,0,0,0,0,0,0};

  const int x2base = xq*32 + w*8;
  const int xs = x2base*2;

  auto ld = [&](const short* r, int x, bool vy)->short8 {
    if (vy && x < 128) return *(const short8*)(r + (long)x*512);
    return zero8;
  };

  short8 L0 = ld(r0, xs, true), L1 = ld(r1, xs, true), L2 = ld(r2, xs, vy2);

#pragma unroll
  for (int i=0;i<8;i++){
    const int x2 = x2base + i;
    const int xm = xs + 2*i + 1, xr = xs + 2*i + 2;
    short8 M0 = ld(r0, xm, true), M1 = ld(r1, xm, true), M2 = ld(r2, xm, vy2);
    short8 R0 = ld(r0, xr, true), R1 = ld(r1, xr, true), R2 = ld(r2, xr, vy2);

    float acc[8];
#pragma unroll
    for (int c=0;c<8;c++) acc[c] = 0.f;
#pragma unroll
    for (int c=0;c<8;c++){
      acc[c] += bf2f((unsigned short)L0[c]) * wv[0][c];
      acc[c] += bf2f((unsigned short)M0[c]) * wv[1][c];
      acc[c] += bf2f((unsigned short)R0[c]) * wv[2][c];
      acc[c] += bf2f((unsigned short)L1[c]) * wv[3][c];
      acc[c] += bf2f((unsigned short)M1[c]) * wv[4][c];
      acc[c] += bf2f((unsigned short)R1[c]) * wv[5][c];
      acc[c] += bf2f((unsigned short)L2[c]) * wv[6][c];
      acc[c] += bf2f((unsigned short)M2[c]) * wv[7][c];
      acc[c] += bf2f((unsigned short)R2[c]) * wv[8][c];
    }
    short8 o;
#pragma unroll
    for (int c=0;c<8;c++) o[c] = (short)f2bf(acc[c]*s[c] + sh[c]);

    if (ch0 < 256) {
      *(short8*)(kv_K + ((long)((b*64+y2)*64 + x2))*256 + ch0) = o;
    } else {
      *(short8*)(&vls[w*8 + i][ch0 - 256]) = o;
    }
    L0 = R0; L1 = R1; L2 = R2;
  }

  __syncthreads();
  {
    const int cc = tid, hh = cc >> 5, d0 = cc & 31;
    long base = ((long)((b*8+hh)*32 + d0))*VT_PLANE + (long)(y2+2)*68 + xq*32 + 2;
#pragma unroll
    for (int j=0;j<16;j++){
      short2 pr;
      pr.x = vls[2*j][cc];
      pr.y = vls[2*j+1][cc];
      *(short2*)(v_t + base + 2*j) = pr;
    }
  }
}

// ---------------- halo attention ---------------------------------------------
// grid 2048 (= 8 batch * 256 windows); 4 waves, wave w -> heads {w, w+4}.
// No barriers; per-wave 8KB XOR-swizzled P in LDS; V from v_t (padded planes);
// in-register norms; exp2-domain logits; O^T epilogue with 8B packed stores.
__global__ __launch_bounds__(256) void halo_attn_kernel(const short* __restrict__ q_buf,
    const short* __restrict__ kv_K, const short* __restrict__ v_t,
    const float* __restrict__ relb, const float* __restrict__ scale,
    short* __restrict__ attn_out)
{
  __shared__ short ps[4][4096];   // per-wave P~ [64 q][64 k] bf16, chunk-swizzled

  const int bid = blockIdx.x;
  const int b = bid >> 8, wno = bid & 255;
  const int bi = wno >> 4, bj = wno & 15;
  const int tid = threadIdx.x;
  const int w = tid >> 6, lane = tid & 63;
  const int g = lane >> 4, q15 = lane & 15;
  short* myps = &ps[w][0];
  const short8 zero8 = {0,0,0,0,0,0,0,0};

  // ---- head-independent per-lane geometry ----
  long kbase[4]; bool kval[4];
#pragma unroll
  for (int m=0;m<4;m++){
    int key = m*16 + q15;
    int yy = bi*4-2 + (key>>3), xx = bj*4-2 + (key&7);
    kval[m] = (yy>=0 && yy<64 && xx>=0 && xx<64);
    kbase[m] = ((long)((b*64+yy)*64+xx))*256 + g*8;
  }
  float mkv[4][4];            // mask in D-layout: key = m*16+g*4+r
#pragma unroll
  for (int m=0;m<4;m++)
#pragma unroll
    for (int r=0;r<4;r++){
      int key = m*16 + g*4 + r;
      int yy = bi*4-2+(key>>3), xx = bj*4-2+(key&7);
      mkv[m][r] = (yy>=0&&yy<64&&xx>=0&&xx<64) ? 0.f : -30000.f;
    }
  long qpix[4];
#pragma unroll
  for (int n=0;n<4;n++){
    int q = n*16+q15;
    qpix[n] = ((long)((b*128+bi*8+(q>>3))*128 + bj*8+(q&7)))*256;
  }
  int voff[2];
#pragma unroll
  for (int ks=0;ks<2;ks++) voff[ks] = (bi*4+ks*4+g)*68 + bj*4;

  for (int hi=0; hi<2; hi++){
    const int h = w + hi*4;
    const float lsc = __expf(fminf(scale[h], 4.6051702f)) * 1.4426950408889634f;

    // ---- V^T A-fragments straight from v_t (issue early; 16B each) ----
    short8 va[2][2];
#pragma unroll
    for (int dblk=0;dblk<2;dblk++){
      long pl = ((long)((b*8+h)*32 + dblk*16 + q15))*VT_PLANE;
#pragma unroll
      for (int ks=0;ks<2;ks++)
        va[dblk][ks] = *(const short8*)(v_t + pl + voff[ks]);
    }

    // ---- K fragments + in-register k norms ----
    short8 af[4]; float rkk[4];
#pragma unroll
    for (int m=0;m<4;m++){
      af[m] = kval[m] ? *(const short8*)(kv_K + kbase[m] + h*32) : zero8;
      float ss = 0.f;
#pragma unroll
      for (int e=0;e<8;e++){ float f = bf2f((unsigned short)af[m][e]); ss += f*f; }
      ss += __shfl_xor(ss, 16);
      ss += __shfl_xor(ss, 32);
      rkk[m] = rsqrtf(fmaxf(ss, 1.55e-5f));
    }
    // ---- Q fragments + in-register q norms (lscale/ln2 folded in) ----
    short8 bfv[4]; float rq[4];
#pragma unroll
    for (int n=0;n<4;n++){
      bfv[n] = *(const short8*)(q_buf + qpix[n] + h*32 + g*8);
      float ss = 0.f;
#pragma unroll
      for (int e=0;e<8;e++){ float f = bf2f((unsigned short)bfv[n][e]); ss += f*f; }
      ss += __shfl_xor(ss, 16);
      ss += __shfl_xor(ss, 32);
      rq[n] = rsqrtf(fmaxf(ss, 1.55e-5f)) * lsc;
    }
    // redistribute k-norms to D-layout (key = m*16+g*4+r)
    float rk[4][4];
#pragma unroll
    for (int m=0;m<4;m++)
#pragma unroll
      for (int r=0;r<4;r++)
        rk[m][r] = __shfl(rkk[m], ((lane>>4)<<2) + r);

    // ---- S^T = K*Q^T ----
    f32x4 sc[4][4];
#pragma unroll
    for (int m=0;m<4;m++)
#pragma unroll
      for (int n=0;n<4;n++)
        sc[m][n] = __builtin_amdgcn_mfma_f32_16x16x32_bf16(af[m], bfv[n],
                       (f32x4){0.f,0.f,0.f,0.f}, 0, 0, 0);

    // ---- logits (exp2 domain) + max ----
    float mx[4] = {-3e38f,-3e38f,-3e38f,-3e38f};
#pragma unroll
    for (int m=0;m<4;m++){
#pragma unroll
      for (int n=0;n<4;n++){
        f32x4 rb = *(const f32x4*)(relb + h*4096 + (n*16+q15)*64 + m*16 + g*4);
#pragma unroll
        for (int r=0;r<4;r++){
          float v = sc[m][n][r] * (rk[m][r]*rq[n]) + rb[r] + mkv[m][r];
          sc[m][n][r] = v;
          mx[n] = fmaxf(mx[n], v);
        }
      }
    }
#pragma unroll
    for (int n=0;n<4;n++){
      mx[n] = fmaxf(mx[n], __shfl_xor(mx[n], 16));
      mx[n] = fmaxf(mx[n], __shfl_xor(mx[n], 32));
    }
    float sm[4] = {0.f,0.f,0.f,0.f};
#pragma unroll
    for (int m=0;m<4;m++)
#pragma unroll
      for (int n=0;n<4;n++)
#pragma unroll
        for (int r=0;r<4;r++){
          float e = exp2f(sc[m][n][r] - mx[n]);
          sc[m][n][r] = e;
          sm[n] += e;
        }
    float sminv[4];
#pragma unroll
    for (int n=0;n<4;n++){
      sm[n] += __shfl_xor(sm[n], 16);
      sm[n] += __shfl_xor(sm[n], 32);
      sminv[n] = 1.f / sm[n];
    }

    // ---- pack P~ (unnormalized, <=1) to LDS, chunk-swizzled ----
#pragma unroll
    for (int n=0;n<4;n++){
      int row = n*16 + q15;
#pragma unroll
      for (int m=0;m<4;m++){
        uint2 pk;
        pk.x = pack_bf_t(sc[m][n][0], sc[m][n][1]);
        pk.y = pack_bf_t(sc[m][n][2], sc[m][n][3]);
        int kc = (m*2 + (g>>1)) ^ (row & 7);
        *(uint2*)(myps + row*64 + kc*8 + ((g&1)<<2)) = pk;
      }
    }
    asm volatile("s_waitcnt lgkmcnt(0)" ::: "memory");

    // ---- O^T = mfma(V^T, P) ----
    f32x4 oc[2][4];
#pragma unroll
    for (int dblk=0;dblk<2;dblk++)
#pragma unroll
      for (int n=0;n<4;n++) oc[dblk][n] = (f32x4){0.f,0.f,0.f,0.f};
#pragma unroll
    for (int ks=0;ks<2;ks++){
#pragma unroll
      for (int n=0;n<4;n++){
        int row = n*16 + q15;
        short8 pb = *(const short8*)(myps + row*64 + (((ks*4+g) ^ (row&7))<<3));
#pragma unroll
        for (int dblk=0;dblk<2;dblk++)
          oc[dblk][n] = __builtin_amdgcn_mfma_f32_16x16x32_bf16(va[dblk][ks], pb, oc[dblk][n], 0, 0, 0);
      }
    }

    // ---- store O (normalize by 1/sum, pack 4 consecutive d = 8B) ----
#pragma unroll
    for (int dblk=0;dblk<2;dblk++){
#pragma unroll
      for (int n=0;n<4;n++){
        uint2 pk;
        pk.x = pack_bf_t(oc[dblk][n][0]*sminv[n], oc[dblk][n][1]*sminv[n]);
        pk.y = pack_bf_t(oc[dblk][n][2]*sminv[n], oc[dblk][n][3]*sminv[n]);
        *(uint2*)(attn_out + qpix[n] + h*32 + dblk*16 + g*4) = pk;
      }
    }
  }
}

// ---------------- launch -----------------------------------------------------
extern "C" void kernel_launch(void* const* d_in, const int* in_sizes, int n_in,
                              void* d_out, int out_size, void* d_ws, size_t ws_size,
                              hipStream_t stream)
{
  (void)in_sizes; (void)n_in; (void)out_size; (void)ws_size;
  const float* inputs = (const float*)d_in[0];
  const float* qkv_w  = (const float*)d_in[1];
  const float* q_bias = (const float*)d_in[2];
  const float* v_bias = (const float*)d_in[3];
  const float* dw_w   = (const float*)d_in[4];
  const float* dw_g   = (const float*)d_in[5];
  const float* dw_b   = (const float*)d_in[6];
  const float* dw_m   = (const float*)d_in[7];
  const float* dw_v   = (const float*)d_in[8];
  const float* scale  = (const float*)d_in[9];
  const float* cpb_w1 = (const float*)d_in[10];
  const float* cpb_b1 = (const float*)d_in[11];
  const float* cpb_w2 = (const float*)d_in[12];
  const float* proj_w = (const float*)d_in[13];
  const float* proj_b = (const float*)d_in[14];

  char* ws = (char*)d_ws;
  short* q_buf    = (short*)(ws);                  //  64 MiB (131072 x 256)
  short* kv_buf   = (short*)(ws + 67108864L);      // 128 MiB (131072 x 512)
  short* kv_K     = (short*)(ws + 201326592L);     //  16 MiB (8x64x64x256)
  short* v_t      = (short*)(ws + 218103808L);     //  ~18 MiB (8*8*32 x 68 x 68)
  short* attn_buf = (short*)(ws + 237043712L);     //  64 MiB (131072 x 256)
  short* qkvw_t   = (short*)(ws + 304152576L);     // 768 KiB
  short* projw_t  = (short*)(ws + 304939008L);     // 128 KiB
  float* relb     = (float*)(ws + 305070080L);     // 128 KiB

  // a_bf reuses the attn_buf region (dead until attention writes it).
  short* a_bf = attn_buf;

  cvt_bf16_kernel<<<2048, 256, 0, stream>>>(inputs, a_bf, 4194304L);
  transpose_w_kernel<<<768, 256, 0, stream>>>(qkv_w, qkvw_t, 256, 768);
  transpose_w_kernel<<<256, 256, 0, stream>>>(proj_w, projw_t, 256, 256);
  relbias_kernel<<<64, 64, 0, stream>>>(cpb_w1, cpb_b1, cpb_w2, relb);

  gemm_bt_kernel<768, 0><<<6144, 256, 0, stream>>>(
      a_bf, qkvw_t, q_bias, q_buf, kv_buf, nullptr);

  dwconv_kernel<<<1024, 256, 0, stream>>>(kv_buf, dw_w, dw_g, dw_b, dw_m, dw_v, v_bias,
                                          kv_K, v_t);

  halo_attn_kernel<<<2048, 256, 0, stream>>>(q_buf, kv_K, v_t, relb, scale, attn_buf);

  gemm_bt_kernel<256, 1><<<2048, 256, 0, stream>>>(
      attn_buf, projw_t, proj_b, nullptr, nullptr, (float*)d_out);
}